// Round 2
// baseline (65.170 us; speedup 1.0000x reference)
//
#include <hip/hip_runtime.h>
#include <math.h>

// Hawkes univariate NLL, O(N) via prefix-scan factorization:
//   S_j = sum_{i<j} exp(-w*(x_j-x_i)) = (1/exp(w*x_j)) * prefix_excl(exp(w*x_i))
// Round 1 was a single-block kernel -> bound by one CU's transcendental pipe
// (~27us floor). This version splits the scan across the chip:
//   K1: per-block sums of y=exp(w*x)  (64 blocks)
//   K2: block-prefix + in-block scan + per-element terms + double atomics
//   K3: finalize scalar loss
// Stream order gives K1->K2->K3 cross-XCD visibility (kernel-boundary coherence).

#define BS 256            // threads per block
#define CHUNK 256         // elements per block (1 per thread)
#define NWAVE (BS / 64)

__launch_bounds__(BS)
__global__ void k1_bsums(const float* __restrict__ x,
                         const float* __restrict__ w_p,
                         float* __restrict__ bsums,
                         double* __restrict__ acc,
                         int NB, int N) {
    const float w = w_p[0];
    const int blk = blockIdx.x;
    const int row = blk / NB, cblk = blk - row * NB;
    const int tid = threadIdx.x, lane = tid & 63, wave = tid >> 6;

    const float y = __expf(w * x[(size_t)row * N + cblk * CHUNK + tid]);

    float v = y;
#pragma unroll
    for (int off = 32; off > 0; off >>= 1) v += __shfl_down(v, off, 64);

    __shared__ float sw[NWAVE];
    if (lane == 0) sw[wave] = v;
    __syncthreads();
    if (tid == 0) {
        float t = 0.0f;
#pragma unroll
        for (int i = 0; i < NWAVE; ++i) t += sw[i];
        bsums[blk] = t;
        if (blk == 0) { acc[0] = 0.0; acc[1] = 0.0; }
    }
}

__launch_bounds__(BS)
__global__ void k2_main(const float* __restrict__ x,
                        const float* __restrict__ mu_p,
                        const float* __restrict__ alpha_p,
                        const float* __restrict__ w_p,
                        const float* __restrict__ bsums,
                        double* __restrict__ acc,
                        int NB, int N) {
    const float mu = mu_p[0], alpha = alpha_p[0], w = w_p[0];
    const float aw = alpha * w;
    const float cneg = __expf(-w);          // exp(-w*(1-x)) = cneg * exp(w*x)

    const int blk = blockIdx.x;
    const int row = blk / NB, cblk = blk - row * NB;
    const int tid = threadIdx.x, lane = tid & 63, wave = tid >> 6;

    const float y = __expf(w * x[(size_t)row * N + cblk * CHUNK + tid]);

    // exclusive prefix from earlier blocks of this row (<=31 L1-hit loads)
    float base = 0.0f;
    for (int i = 0; i < cblk; ++i) base += bsums[row * NB + i];

    // in-block exclusive scan of y: wave shuffle scan + wave offsets via LDS
    float v = y;
#pragma unroll
    for (int off = 1; off < 64; off <<= 1) {
        float n = __shfl_up(v, off, 64);
        if (lane >= off) v += n;
    }
    __shared__ float sw[NWAVE];
    if (lane == 63) sw[wave] = v;
    __syncthreads();
    float woff = 0.0f;
#pragma unroll
    for (int i = 0; i < NWAVE; ++i) if (i < wave) woff += sw[i];
    const float prefix = base + woff + (v - y);   // exclusive prefix of exp(w*x_i)

    const float S   = prefix / y;                 // exp(-w*x_j) * prefix
    const float pos = __logf(mu + aw * S);
    const float neg = alpha * (1.0f - cneg * y);

    double pd = (double)pos, nd = (double)neg;
#pragma unroll
    for (int off = 32; off > 0; off >>= 1) {
        pd += __shfl_down(pd, off, 64);
        nd += __shfl_down(nd, off, 64);
    }
    __shared__ double sp[NWAVE], sn[NWAVE];
    if (lane == 0) { sp[wave] = pd; sn[wave] = nd; }
    __syncthreads();
    if (tid == 0) {
        double P = 0.0, Ng = 0.0;
#pragma unroll
        for (int i = 0; i < NWAVE; ++i) { P += sp[i]; Ng += sn[i]; }
        atomicAdd(&acc[0], P);
        atomicAdd(&acc[1], Ng);
    }
}

__global__ void k3_final(const float* __restrict__ mu_p,
                         const float* __restrict__ alpha_p,
                         const float* __restrict__ w_p,
                         const double* __restrict__ acc,
                         float* __restrict__ out) {
    if (threadIdx.x == 0 && blockIdx.x == 0) {
        const double mu = mu_p[0], alpha = alpha_p[0], w = w_p[0];
        const double T_HORIZON = 1.0, REG = 0.01;
        double loss = mu * T_HORIZON - acc[0] + acc[1]
                    + REG * (-log(mu) - log(alpha) - log(w));
        out[0] = (float)loss;
    }
}

extern "C" void kernel_launch(void* const* d_in, const int* in_sizes, int n_in,
                              void* d_out, int out_size, void* d_ws, size_t ws_size,
                              hipStream_t stream) {
    const float* x     = (const float*)d_in[0];
    const float* mu    = (const float*)d_in[1];
    const float* alpha = (const float*)d_in[2];
    const float* w     = (const float*)d_in[3];
    float* out = (float*)d_out;

    const int N  = 8192;
    const int B  = in_sizes[0] / N;     // 2
    const int NB = N / CHUNK;           // 32
    const int nblk = B * NB;            // 64

    double* acc   = (double*)d_ws;            // acc[0]=sum(pos), acc[1]=sum(neg)
    float*  bsums = (float*)(acc + 2);        // B*NB block sums

    hipLaunchKernelGGL(k1_bsums, dim3(nblk), dim3(BS), 0, stream,
                       x, w, bsums, acc, NB, N);
    hipLaunchKernelGGL(k2_main, dim3(nblk), dim3(BS), 0, stream,
                       x, mu, alpha, w, bsums, acc, NB, N);
    hipLaunchKernelGGL(k3_final, dim3(1), dim3(64), 0, stream,
                       mu, alpha, w, acc, out);
}